// Round 8
// baseline (422.093 us; speedup 1.0000x reference)
//
#include <hip/hip_runtime.h>
#include <hip/hip_bf16.h>
#include <math.h>

#define NCOL 192   // 64 root | 64 rel0 | 64 rel1
#define BB   30    // bases
#define SCAN_T 256
#define SCAN_ELEMS 1024   // per scan block (4 per thread)

typedef short bf16x8 __attribute__((ext_vector_type(8)));
typedef float f32x4  __attribute__((ext_vector_type(4)));
typedef unsigned short u16x8 __attribute__((ext_vector_type(8)));

__device__ __forceinline__ ushort f2bf(float f) {
  unsigned u = __float_as_uint(f);
  unsigned r = u + 0x7fff + ((u >> 16) & 1);   // RTNE
  return (ushort)(r >> 16);
}
__device__ __forceinline__ float bf2f(ushort u) {
  return __uint_as_float(((unsigned)u) << 16);
}

// ---------------- CSR build ----------------
__global__ void hist_deg(const int* __restrict__ dst, int* __restrict__ deg, int E) {
  int e = blockIdx.x * blockDim.x + threadIdx.x;
  if (e >= E) return;
  atomicAdd(&deg[dst[e]], 1);
}

// per-block exclusive scan of deg -> rowptr[0..N] (LOCAL, no partial added),
// block totals -> partial[b]. Consumers add partial[i>>10] on the fly.
__global__ __launch_bounds__(SCAN_T) void scan_local(const int* __restrict__ deg,
                                                     int* __restrict__ rowptr,
                                                     int* __restrict__ partial, int N) {
  __shared__ int sdata[SCAN_T];
  int t = threadIdx.x;
  int base = blockIdx.x * SCAN_ELEMS + t * 4;
  int v[4], s = 0;
#pragma unroll
  for (int k = 0; k < 4; ++k) {
    v[k] = (base + k < N) ? deg[base + k] : 0;
    s += v[k];
  }
  sdata[t] = s;
  __syncthreads();
  for (int off = 1; off < SCAN_T; off <<= 1) {
    int add = (t >= off) ? sdata[t - off] : 0;
    __syncthreads();
    sdata[t] += add;
    __syncthreads();
  }
  int run = sdata[t] - s;  // exclusive prefix of this thread's chunk
  if (t == SCAN_T - 1) partial[blockIdx.x] = sdata[t];
#pragma unroll
  for (int k = 0; k < 4; ++k) {
    if (base + k <= N) rowptr[base + k] = run;   // includes index N
    run += v[k];
  }
}

// single-block exclusive scan of partial[0..nb)
__global__ __launch_bounds__(SCAN_T) void scan_partial(int* __restrict__ partial, int nb) {
  __shared__ int sdata[SCAN_T];
  int t = threadIdx.x;
  int v = (t < nb) ? partial[t] : 0;
  sdata[t] = v;
  __syncthreads();
  for (int off = 1; off < SCAN_T; off <<= 1) {
    int add = (t >= off) ? sdata[t - off] : 0;
    __syncthreads();
    sdata[t] += add;
    __syncthreads();
  }
  if (t < nb) partial[t] = sdata[t] - v;
  if (t == nb - 1) partial[nb] = sdata[t];
}

__global__ void scatter_edges(const int* __restrict__ src, const int* __restrict__ dst,
                              const int* __restrict__ et, const int* __restrict__ rowptr,
                              const int* __restrict__ partial,
                              int* __restrict__ fill, int* __restrict__ srcpk, int E) {
  int e = blockIdx.x * blockDim.x + threadIdx.x;
  if (e >= E) return;
  int d = dst[e];
  int pos = rowptr[d] + partial[d >> 10] + atomicAdd(&fill[d], 1);
  srcpk[pos] = src[e] | (et[e] << 30);
}

// ---------------- weights (both layers in one dispatch) ----------------
__device__ __forceinline__ void wpk_one(const float* __restrict__ basis,
                                        const float* __restrict__ comp,
                                        const float* __restrict__ root,
                                        ushort* __restrict__ Wpk, int Kin, int idx) {
  int k = idx / NCOL, j = idx - k * NCOL;
  float v;
  if (j < 64) {
    v = root[k * 64 + j];
  } else {
    int r = (j >> 6) - 1, o = j & 63;
    float s = 0.f;
#pragma unroll
    for (int b = 0; b < BB; ++b)
      s = fmaf(comp[r * BB + b], basis[((size_t)b * Kin + k) * 64 + o], s);
    v = s;
  }
  Wpk[(((size_t)(k >> 3) * NCOL + j) << 3) + (k & 7)] = f2bf(v);
}

__global__ void build_wpk_both(const float* __restrict__ basis1, const float* __restrict__ comp1,
                               const float* __restrict__ root1,
                               const float* __restrict__ basis2, const float* __restrict__ comp2,
                               const float* __restrict__ root2,
                               ushort* __restrict__ Wpk1, ushort* __restrict__ Wpk2) {
  int idx = blockIdx.x * blockDim.x + threadIdx.x;
  if (idx < 512 * NCOL) {
    wpk_one(basis1, comp1, root1, Wpk1, 512, idx);
  } else {
    idx -= 512 * NCOL;
    if (idx < 64 * NCOL) wpk_one(basis2, comp2, root2, Wpk2, 64, idx);
  }
}

// ---------------- GEMM (MFMA bf16, split-col waves, 2-deep pipelined dbuf) ----------------
template <int K, int BF16IN>
__global__ __launch_bounds__(256, 4) void gemm_mfma(const void* __restrict__ Xv,
                                                    const ushort* __restrict__ Wpk,
                                                    ushort* __restrict__ Y, int N) {
  constexpr int BK  = 64;
  constexpr int NC  = K / BK;
  constexpr int NLD = BF16IN ? (64 * (BK / 8) / 256) : (64 * (BK / 4) / 256);
  __shared__ ushort As[(NC > 1 ? 2 : 1) * 64 * BK];

  const int row0 = blockIdx.x * 64;
  const int tid  = threadIdx.x;
  const int wid  = tid >> 6;
  const int lane = tid & 63;
  const int lrow = lane & 15;
  const int lhi  = lane >> 4;

  const float*  Xf = (const float*)Xv;
  const ushort* Xh = (const ushort*)Xv;

  // two prefetch register sets (A: even chunks, B: odd chunks)
  float4 pfA[BF16IN ? 1 : NLD], pfB[BF16IN ? 1 : NLD];
  u16x8  phA[BF16IN ? NLD : 1], phB[BF16IN ? NLD : 1];

#define LOAD_CHUNK(c, PF, PH)                                                       \
  if constexpr (BF16IN) {                                                           \
    _Pragma("unroll") for (int it = 0; it < NLD; ++it) {                            \
      int idx = tid + it * 256;                                                     \
      int row = idx / (BK / 8), kq = idx - row * (BK / 8);                          \
      int r = row0 + row;                                                           \
      PH[it] = (u16x8){0, 0, 0, 0, 0, 0, 0, 0};                                     \
      if (r < N) PH[it] = ((const u16x8*)Xh)[(size_t)r * (K / 8) + (c) * (BK / 8) + kq]; \
    }                                                                               \
  } else {                                                                          \
    _Pragma("unroll") for (int it = 0; it < NLD; ++it) {                            \
      int idx = tid + it * 256;                                                     \
      int row = idx / (BK / 4), kq = idx - row * (BK / 4);                          \
      int r = row0 + row;                                                           \
      PF[it] = make_float4(0.f, 0.f, 0.f, 0.f);                                     \
      if (r < N) PF[it] = ((const float4*)Xf)[(size_t)r * (K / 4) + (c) * (BK / 4) + kq]; \
    }                                                                               \
  }

#define COMMIT_CHUNK(buf, PF, PH)                                                   \
  {                                                                                 \
    char* Aw = (char*)As + (size_t)(buf) * 64 * BK * 2;                             \
    if constexpr (BF16IN) {                                                         \
      _Pragma("unroll") for (int it = 0; it < NLD; ++it) {                          \
        int idx = tid + it * 256;                                                   \
        int row = idx / (BK / 8), kq = idx - row * (BK / 8);                        \
        int byte = ((row * BK + kq * 8) * 2) ^ ((row & 7) << 4);                    \
        *(u16x8*)(Aw + byte) = PH[it];                                              \
      }                                                                             \
    } else {                                                                        \
      _Pragma("unroll") for (int it = 0; it < NLD; ++it) {                          \
        int idx = tid + it * 256;                                                   \
        int row = idx / (BK / 4), kq = idx - row * (BK / 4);                        \
        ushort4 b;                                                                  \
        b.x = f2bf(PF[it].x); b.y = f2bf(PF[it].y);                                 \
        b.z = f2bf(PF[it].z); b.w = f2bf(PF[it].w);                                 \
        int byte = ((row * BK + kq * 4) * 2) ^ ((row & 7) << 4);                    \
        *(ushort4*)(Aw + byte) = b;                                                 \
      }                                                                             \
    }                                                                               \
  }

  // prologue: chunk 0 staged; chunk 1 loads issued (land during chunk-0 MFMA)
  LOAD_CHUNK(0, pfA, phA)
  COMMIT_CHUNK(0, pfA, phA)
  if constexpr (NC > 1) { LOAD_CHUNK(1, pfB, phB) }
  __syncthreads();

  f32x4 acc[4][3];
#pragma unroll
  for (int s = 0; s < 4; ++s)
#pragma unroll
    for (int c = 0; c < 3; ++c) acc[s][c] = (f32x4){0.f, 0.f, 0.f, 0.f};

#pragma unroll
  for (int c = 0; c < NC; ++c) {
    if (c + 2 < NC) {  // issue loads 2 chunks ahead into the freed register set
      if ((c & 1) == 0) { LOAD_CHUNK(c + 2, pfA, phA) }
      else              { LOAD_CHUNK(c + 2, pfB, phB) }
    }
    const char* Ab = (const char*)As + (size_t)(NC > 1 ? (c & 1) : 0) * 64 * BK * 2;
#pragma unroll
    for (int t = 0; t < BK / 32; ++t) {
      int g = (c * (BK / 32) + t) * 4 + lhi;  // bf16x8 k-group index
      const bf16x8* bp = (const bf16x8*)Wpk + (size_t)g * NCOL + wid * 48 + lrow;
      bf16x8 b0 = bp[0];
      bf16x8 b1 = bp[16];
      bf16x8 b2 = bp[32];
      bf16x8 a[4];
#pragma unroll
      for (int s = 0; s < 4; ++s) {
        int arow = s * 16 + lrow;
        int abyte = ((arow * BK + t * 32 + lhi * 8) * 2) ^ ((arow & 7) << 4);
        a[s] = *(const bf16x8*)(Ab + abyte);
      }
#pragma unroll
      for (int s = 0; s < 4; ++s) {
        acc[s][0] = __builtin_amdgcn_mfma_f32_16x16x32_bf16(a[s], b0, acc[s][0], 0, 0, 0);
        acc[s][1] = __builtin_amdgcn_mfma_f32_16x16x32_bf16(a[s], b1, acc[s][1], 0, 0, 0);
        acc[s][2] = __builtin_amdgcn_mfma_f32_16x16x32_bf16(a[s], b2, acc[s][2], 0, 0, 0);
      }
    }
    if (c + 1 < NC) {
      // buf[(c+1)&1]'s last reader was MFMA(c-1), fenced by the previous barrier:
      // safe to commit without a pre-barrier. One barrier per chunk.
      if (((c + 1) & 1) == 0) { COMMIT_CHUNK(0, pfA, phA) }
      else                    { COMMIT_CHUNK(1, pfB, phB) }
      __syncthreads();
    }
  }
#undef LOAD_CHUNK
#undef COMMIT_CHUNK

  // C/D: col = lane&15, row = (lane>>4)*4 + reg   [m89]
#pragma unroll
  for (int s = 0; s < 4; ++s) {
#pragma unroll
    for (int cc = 0; cc < 3; ++cc) {
#pragma unroll
      for (int j = 0; j < 4; ++j) {
        int r = row0 + s * 16 + lhi * 4 + j;
        if (r < N) Y[(size_t)r * NCOL + wid * 48 + cc * 16 + lrow] = f2bf(acc[s][cc][j]);
      }
    }
  }
}

// ---------------- fused per-node aggregation (8 edges per gather instr) ----------------
template <int RELU, int GATH>
__global__ __launch_bounds__(256) void fused_agg(const ushort* __restrict__ Y,
                                                 const int* __restrict__ rowptr,
                                                 const int* __restrict__ partial,
                                                 const int* __restrict__ srcpk,
                                                 const float* __restrict__ bias,
                                                 const float* __restrict__ gw,
                                                 ushort* __restrict__ accout,
                                                 float* __restrict__ hval, int N) {
  int n = blockIdx.x * 4 + (threadIdx.x >> 6);
  if (n >= N) return;
  const int lane = threadIdx.x & 63;
  const int g    = lane >> 3;        // edge slot 0..7
  const int f0   = (lane & 7) * 8;   // feature slice

  float a0[8], a1[8];
#pragma unroll
  for (int j = 0; j < 8; ++j) { a0[j] = 0.f; a1[j] = 0.f; }
  float c0 = 0.f, c1 = 0.f;

  const int beg = rowptr[n] + partial[n >> 10];
  const int end = rowptr[n + 1] + partial[(n + 1) >> 10];
  for (int i = beg; i < end; i += 16) {
    int eA = i + g, eB = i + 8 + g;
    bool vA = eA < end, vB = eB < end;
    int pkA = 0, pkB = 0;
    if (vA) pkA = srcpk[eA];
    if (vB) pkB = srcpk[eB];
    u16x8 xA = (u16x8){0, 0, 0, 0, 0, 0, 0, 0}, xB = xA;
    if (vA) xA = *(const u16x8*)(Y + (size_t)(pkA & 0x3fffffff) * NCOL + 64 +
                                 ((pkA >> 30) << 6) + f0);
    if (vB) xB = *(const u16x8*)(Y + (size_t)(pkB & 0x3fffffff) * NCOL + 64 +
                                 ((pkB >> 30) << 6) + f0);
    float rA = (vA && (pkA >> 30)) ? 1.f : 0.f;
    float sA = vA ? 1.f : 0.f;
    float rB = (vB && (pkB >> 30)) ? 1.f : 0.f;
    float sB = vB ? 1.f : 0.f;
    c0 += (sA - rA) + (sB - rB);
    c1 += rA + rB;
#pragma unroll
    for (int j = 0; j < 8; ++j) {
      float fA = bf2f(xA[j]), fB = bf2f(xB[j]);
      a0[j] += (sA - rA) * fA + (sB - rB) * fB;
      a1[j] += rA * fA + rB * fB;
    }
  }

  // fold the 8 edge-groups
#pragma unroll
  for (int msk = 8; msk <= 32; msk <<= 1) {
#pragma unroll
    for (int j = 0; j < 8; ++j) {
      a0[j] += __shfl_xor(a0[j], msk);
      a1[j] += __shfl_xor(a1[j], msk);
    }
    c0 += __shfl_xor(c0, msk);
    c1 += __shfl_xor(c1, msk);
  }

  float inv0 = 1.f / fmaxf(c0, 1.f);
  float inv1 = 1.f / fmaxf(c1, 1.f);
  u16x8 rv = *(const u16x8*)(Y + (size_t)n * NCOL + f0);
  float4 bA = *(const float4*)(bias + f0);
  float4 bB = *(const float4*)(bias + f0 + 4);
  float bb[8] = {bA.x, bA.y, bA.z, bA.w, bB.x, bB.y, bB.z, bB.w};
  float res[8];
#pragma unroll
  for (int j = 0; j < 8; ++j) {
    float v = bf2f(rv[j]) + bb[j] + a0[j] * inv0 + a1[j] * inv1;
    res[j] = RELU ? fmaxf(v, 0.f) : v;
  }
  if (accout && g == 0) {
    u16x8 o;
#pragma unroll
    for (int j = 0; j < 8; ++j) o[j] = f2bf(res[j]);
    *(u16x8*)(accout + (size_t)n * 64 + f0) = o;
  }
  if (GATH) {
    float4 gA = *(const float4*)(gw + f0);
    float4 gB = *(const float4*)(gw + f0 + 4);
    float gg[8] = {gA.x, gA.y, gA.z, gA.w, gB.x, gB.y, gB.z, gB.w};
    float dot = 0.f;
#pragma unroll
    for (int j = 0; j < 8; ++j) dot = fmaf(res[j], gg[j], dot);
    dot += __shfl_xor(dot, 1);
    dot += __shfl_xor(dot, 2);
    dot += __shfl_xor(dot, 4);
    if (lane == 0) hval[n] = dot;
  }
}

// ---------------- GAT (CSR, wave per node, lane per edge) ----------------
__device__ __forceinline__ float leaky(float x) { return x > 0.f ? x : 0.2f * x; }

__global__ __launch_bounds__(256) void gat_csr(const int* __restrict__ rowptr,
                                               const int* __restrict__ partial,
                                               const int* __restrict__ srcpk,
                                               const float* __restrict__ hval,
                                               const float* __restrict__ as_,
                                               const float* __restrict__ ad_,
                                               const float* __restrict__ gb,
                                               float* __restrict__ out, int N) {
  int n = blockIdx.x * 4 + (threadIdx.x >> 6);
  if (n >= N) return;
  const int lane = threadIdx.x & 63;
  float as = *as_, ad = *ad_;
  float hv = hval[n];
  float adn = hv * ad;
  float eself = leaky(hv * as + adn);
  const int beg = rowptr[n] + partial[n >> 10];
  const int end = rowptr[n + 1] + partial[(n + 1) >> 10];
  int deg = end - beg;
  float m, den, acc;
  if (deg <= 64) {  // single pass, everything in registers
    bool valid = lane < deg;
    float hs = 0.f;
    if (valid) hs = hval[srcpk[beg + lane] & 0x3fffffff];
    float e = valid ? leaky(hs * as + adn) : -3.4e38f;
    m = fmaxf(e, eself);
#pragma unroll
    for (int o = 32; o > 0; o >>= 1) m = fmaxf(m, __shfl_xor(m, o));
    float ex = valid ? expf(e - m) : 0.f;
    den = ex;
    acc = ex * hs;
#pragma unroll
    for (int o = 32; o > 0; o >>= 1) {
      den += __shfl_xor(den, o);
      acc += __shfl_xor(acc, o);
    }
  } else {  // rare: strided two-pass
    m = eself;
    for (int i = beg + lane; i < end; i += 64)
      m = fmaxf(m, leaky(hval[srcpk[i] & 0x3fffffff] * as + adn));
#pragma unroll
    for (int o = 32; o > 0; o >>= 1) m = fmaxf(m, __shfl_xor(m, o));
    float dl = 0.f, al = 0.f;
    for (int i = beg + lane; i < end; i += 64) {
      float hs = hval[srcpk[i] & 0x3fffffff];
      float ex = expf(leaky(hs * as + adn) - m);
      dl += ex;
      al += ex * hs;
    }
    den = dl;
    acc = al;
#pragma unroll
    for (int o = 32; o > 0; o >>= 1) {
      den += __shfl_xor(den, o);
      acc += __shfl_xor(acc, o);
    }
  }
  float es = expf(eself - m);
  den += es;
  acc += es * hv;
  if (lane == 0) out[n] = acc / den + *gb;
}

// ---------------- launch ----------------
extern "C" void kernel_launch(void* const* d_in, const int* in_sizes, int n_in,
                              void* d_out, int out_size, void* d_ws, size_t ws_size,
                              hipStream_t stream) {
  const float* x      = (const float*)d_in[0];
  const int*   eidx   = (const int*)d_in[1];
  const int*   etype  = (const int*)d_in[2];
  const float* basis1 = (const float*)d_in[3];
  const float* comp1  = (const float*)d_in[4];
  const float* root1  = (const float*)d_in[5];
  const float* bias1  = (const float*)d_in[6];
  const float* basis2 = (const float*)d_in[7];
  const float* comp2  = (const float*)d_in[8];
  const float* root2  = (const float*)d_in[9];
  const float* bias2  = (const float*)d_in[10];
  const float* gat_w  = (const float*)d_in[11];
  const float* att_s  = (const float*)d_in[12];
  const float* att_d  = (const float*)d_in[13];
  const float* gat_b  = (const float*)d_in[14];

  const int N = in_sizes[0] / 512;   // 100000
  const int E = in_sizes[1] / 2;     // 1600000
  const int* src = eidx;
  const int* dst = eidx + E;

  // workspace carve-up (16B-aligned segments)
  char* p = (char*)d_ws;
  ushort* Y    = (ushort*)p; p += (size_t)N * NCOL * 2;        // 38.4 MB (bf16)
  ushort* acc1 = (ushort*)p; p += (size_t)N * 64 * 2;          // 12.8 MB (bf16)
  ushort* Wpk1 = (ushort*)p; p += (size_t)512 * NCOL * 2;      // 196 KB
  ushort* Wpk2 = (ushort*)p; p += (size_t)64 * NCOL * 2;       // 24.6 KB
  float* hval  = (float*)p;  p += (size_t)N * 4;
  int* deg     = (int*)p;    p += (size_t)N * 4;               // zeroed together
  int* fill    = (int*)p;    p += (size_t)N * 4;               //  (one memset)
  int* rowptr  = (int*)p;    p += (size_t)(N + 16) * 4;
  int* partial = (int*)p;    p += (size_t)(SCAN_T + 16) * 4;
  int* srcpk   = (int*)p;    p += (size_t)E * 4;               // 6.4 MB
  float* out   = (float*)d_out;

  const int TB = 256;
  const int GB = (N + 63) / 64;
  const int nb = (N + 1 + SCAN_ELEMS - 1) / SCAN_ELEMS;

  // ---- CSR build (shared by both layers and GAT) ----
  hipMemsetAsync(deg, 0, (size_t)2 * N * sizeof(int), stream);  // deg + fill
  hist_deg<<<(E + TB - 1) / TB, TB, 0, stream>>>(dst, deg, E);
  scan_local<<<nb, SCAN_T, 0, stream>>>(deg, rowptr, partial, N);
  scan_partial<<<1, SCAN_T, 0, stream>>>(partial, nb);
  scatter_edges<<<(E + TB - 1) / TB, TB, 0, stream>>>(src, dst, etype, rowptr, partial,
                                                      fill, srcpk, E);

  // ---- weights (both layers, one dispatch) ----
  build_wpk_both<<<(576 * NCOL + TB - 1) / TB, TB, 0, stream>>>(basis1, comp1, root1,
                                                                basis2, comp2, root2,
                                                                Wpk1, Wpk2);

  // ---- layer 1 (K=512, f32 input) ----
  gemm_mfma<512, 0><<<GB, 256, 0, stream>>>(x, Wpk1, Y, N);
  fused_agg<1, 0><<<(N + 3) / 4, TB, 0, stream>>>(Y, rowptr, partial, srcpk, bias1, nullptr,
                                                  acc1, nullptr, N);

  // ---- layer 2 (K=64, bf16 input) ----
  gemm_mfma<64, 1><<<GB, 256, 0, stream>>>(acc1, Wpk2, Y, N);
  fused_agg<0, 1><<<(N + 3) / 4, TB, 0, stream>>>(Y, rowptr, partial, srcpk, bias2, gat_w,
                                                  nullptr, hval, N);

  // ---- GAT ----
  gat_csr<<<(N + 3) / 4, TB, 0, stream>>>(rowptr, partial, srcpk, hval, att_s, att_d, gat_b,
                                          out, N);
}

// Round 9
// 420.130 us; speedup vs baseline: 1.0047x; 1.0047x over previous
//
#include <hip/hip_runtime.h>
#include <hip/hip_bf16.h>
#include <math.h>

#define NCOL 192   // 64 root | 64 rel0 | 64 rel1
#define BB   30    // bases
#define SCAN_T 256
#define SCAN_ELEMS 1024   // per scan block (4 per thread)

typedef short bf16x8 __attribute__((ext_vector_type(8)));
typedef float f32x4  __attribute__((ext_vector_type(4)));
typedef unsigned short u16x8 __attribute__((ext_vector_type(8)));

__device__ __forceinline__ ushort f2bf(float f) {
  unsigned u = __float_as_uint(f);
  unsigned r = u + 0x7fff + ((u >> 16) & 1);   // RTNE
  return (ushort)(r >> 16);
}
__device__ __forceinline__ float bf2f(ushort u) {
  return __uint_as_float(((unsigned)u) << 16);
}

// ---------------- CSR build ----------------
__global__ void hist_deg(const int* __restrict__ dst, int* __restrict__ deg, int E) {
  int e = blockIdx.x * blockDim.x + threadIdx.x;
  if (e >= E) return;
  atomicAdd(&deg[dst[e]], 1);
}

// per-block exclusive scan of deg -> rowptr[0..N] (LOCAL, no partial added),
// block totals -> partial[b]. Consumers add partial[i>>10] on the fly.
__global__ __launch_bounds__(SCAN_T) void scan_local(const int* __restrict__ deg,
                                                     int* __restrict__ rowptr,
                                                     int* __restrict__ partial, int N) {
  __shared__ int sdata[SCAN_T];
  int t = threadIdx.x;
  int base = blockIdx.x * SCAN_ELEMS + t * 4;
  int v[4], s = 0;
#pragma unroll
  for (int k = 0; k < 4; ++k) {
    v[k] = (base + k < N) ? deg[base + k] : 0;
    s += v[k];
  }
  sdata[t] = s;
  __syncthreads();
  for (int off = 1; off < SCAN_T; off <<= 1) {
    int add = (t >= off) ? sdata[t - off] : 0;
    __syncthreads();
    sdata[t] += add;
    __syncthreads();
  }
  int run = sdata[t] - s;  // exclusive prefix of this thread's chunk
  if (t == SCAN_T - 1) partial[blockIdx.x] = sdata[t];
#pragma unroll
  for (int k = 0; k < 4; ++k) {
    if (base + k <= N) rowptr[base + k] = run;   // includes index N
    run += v[k];
  }
}

// single-block exclusive scan of partial[0..nb)
__global__ __launch_bounds__(SCAN_T) void scan_partial(int* __restrict__ partial, int nb) {
  __shared__ int sdata[SCAN_T];
  int t = threadIdx.x;
  int v = (t < nb) ? partial[t] : 0;
  sdata[t] = v;
  __syncthreads();
  for (int off = 1; off < SCAN_T; off <<= 1) {
    int add = (t >= off) ? sdata[t - off] : 0;
    __syncthreads();
    sdata[t] += add;
    __syncthreads();
  }
  if (t < nb) partial[t] = sdata[t] - v;
  if (t == nb - 1) partial[nb] = sdata[t];
}

__global__ void scatter_edges(const int* __restrict__ src, const int* __restrict__ dst,
                              const int* __restrict__ et, const int* __restrict__ rowptr,
                              const int* __restrict__ partial,
                              int* __restrict__ fill, int* __restrict__ srcpk, int E) {
  int e = blockIdx.x * blockDim.x + threadIdx.x;
  if (e >= E) return;
  int d = dst[e];
  int pos = rowptr[d] + partial[d >> 10] + atomicAdd(&fill[d], 1);
  srcpk[pos] = src[e] | (et[e] << 30);
}

// ---------------- weights (both layers in one dispatch) ----------------
__device__ __forceinline__ void wpk_one(const float* __restrict__ basis,
                                        const float* __restrict__ comp,
                                        const float* __restrict__ root,
                                        ushort* __restrict__ Wpk, int Kin, int idx) {
  int k = idx / NCOL, j = idx - k * NCOL;
  float v;
  if (j < 64) {
    v = root[k * 64 + j];
  } else {
    int r = (j >> 6) - 1, o = j & 63;
    float s = 0.f;
#pragma unroll
    for (int b = 0; b < BB; ++b)
      s = fmaf(comp[r * BB + b], basis[((size_t)b * Kin + k) * 64 + o], s);
    v = s;
  }
  Wpk[(((size_t)(k >> 3) * NCOL + j) << 3) + (k & 7)] = f2bf(v);
}

__global__ void build_wpk_both(const float* __restrict__ basis1, const float* __restrict__ comp1,
                               const float* __restrict__ root1,
                               const float* __restrict__ basis2, const float* __restrict__ comp2,
                               const float* __restrict__ root2,
                               ushort* __restrict__ Wpk1, ushort* __restrict__ Wpk2) {
  int idx = blockIdx.x * blockDim.x + threadIdx.x;
  if (idx < 512 * NCOL) {
    wpk_one(basis1, comp1, root1, Wpk1, 512, idx);
  } else {
    idx -= 512 * NCOL;
    if (idx < 64 * NCOL) wpk_one(basis2, comp2, root2, Wpk2, 64, idx);
  }
}

// ---------------- GEMM (MFMA bf16, split-col waves, 2-deep pipelined dbuf) ----------------
template <int K, int BF16IN>
__global__ __launch_bounds__(256, 4) void gemm_mfma(const void* __restrict__ Xv,
                                                    const ushort* __restrict__ Wpk,
                                                    ushort* __restrict__ Y, int N) {
  constexpr int BK  = 64;
  constexpr int NC  = K / BK;
  constexpr int NLD = BF16IN ? (64 * (BK / 8) / 256) : (64 * (BK / 4) / 256);
  __shared__ ushort As[(NC > 1 ? 2 : 1) * 64 * BK];

  const int row0 = blockIdx.x * 64;
  const int tid  = threadIdx.x;
  const int wid  = tid >> 6;
  const int lane = tid & 63;
  const int lrow = lane & 15;
  const int lhi  = lane >> 4;

  const float*  Xf = (const float*)Xv;
  const ushort* Xh = (const ushort*)Xv;

  // two prefetch register sets (A: even chunks, B: odd chunks)
  float4 pfA[BF16IN ? 1 : NLD], pfB[BF16IN ? 1 : NLD];
  u16x8  phA[BF16IN ? NLD : 1], phB[BF16IN ? NLD : 1];

#define LOAD_CHUNK(c, PF, PH)                                                       \
  if constexpr (BF16IN) {                                                           \
    _Pragma("unroll") for (int it = 0; it < NLD; ++it) {                            \
      int idx = tid + it * 256;                                                     \
      int row = idx / (BK / 8), kq = idx - row * (BK / 8);                          \
      int r = row0 + row;                                                           \
      PH[it] = (u16x8){0, 0, 0, 0, 0, 0, 0, 0};                                     \
      if (r < N) PH[it] = ((const u16x8*)Xh)[(size_t)r * (K / 8) + (c) * (BK / 8) + kq]; \
    }                                                                               \
  } else {                                                                          \
    _Pragma("unroll") for (int it = 0; it < NLD; ++it) {                            \
      int idx = tid + it * 256;                                                     \
      int row = idx / (BK / 4), kq = idx - row * (BK / 4);                          \
      int r = row0 + row;                                                           \
      PF[it] = make_float4(0.f, 0.f, 0.f, 0.f);                                     \
      if (r < N) PF[it] = ((const float4*)Xf)[(size_t)r * (K / 4) + (c) * (BK / 4) + kq]; \
    }                                                                               \
  }

#define COMMIT_CHUNK(buf, PF, PH)                                                   \
  {                                                                                 \
    char* Aw = (char*)As + (size_t)(buf) * 64 * BK * 2;                             \
    if constexpr (BF16IN) {                                                         \
      _Pragma("unroll") for (int it = 0; it < NLD; ++it) {                          \
        int idx = tid + it * 256;                                                   \
        int row = idx / (BK / 8), kq = idx - row * (BK / 8);                        \
        int byte = ((row * BK + kq * 8) * 2) ^ ((row & 7) << 4);                    \
        *(u16x8*)(Aw + byte) = PH[it];                                              \
      }                                                                             \
    } else {                                                                        \
      _Pragma("unroll") for (int it = 0; it < NLD; ++it) {                          \
        int idx = tid + it * 256;                                                   \
        int row = idx / (BK / 4), kq = idx - row * (BK / 4);                        \
        ushort4 b;                                                                  \
        b.x = f2bf(PF[it].x); b.y = f2bf(PF[it].y);                                 \
        b.z = f2bf(PF[it].z); b.w = f2bf(PF[it].w);                                 \
        int byte = ((row * BK + kq * 4) * 2) ^ ((row & 7) << 4);                    \
        *(ushort4*)(Aw + byte) = b;                                                 \
      }                                                                             \
    }                                                                               \
  }

  // prologue: chunk 0 staged; chunk 1 loads issued (land during chunk-0 MFMA)
  LOAD_CHUNK(0, pfA, phA)
  COMMIT_CHUNK(0, pfA, phA)
  if constexpr (NC > 1) { LOAD_CHUNK(1, pfB, phB) }
  __syncthreads();

  f32x4 acc[4][3];
#pragma unroll
  for (int s = 0; s < 4; ++s)
#pragma unroll
    for (int c = 0; c < 3; ++c) acc[s][c] = (f32x4){0.f, 0.f, 0.f, 0.f};

#pragma unroll
  for (int c = 0; c < NC; ++c) {
    if (c + 2 < NC) {  // issue loads 2 chunks ahead into the freed register set
      if ((c & 1) == 0) { LOAD_CHUNK(c + 2, pfA, phA) }
      else              { LOAD_CHUNK(c + 2, pfB, phB) }
    }
    const char* Ab = (const char*)As + (size_t)(NC > 1 ? (c & 1) : 0) * 64 * BK * 2;
#pragma unroll
    for (int t = 0; t < BK / 32; ++t) {
      int g = (c * (BK / 32) + t) * 4 + lhi;  // bf16x8 k-group index
      const bf16x8* bp = (const bf16x8*)Wpk + (size_t)g * NCOL + wid * 48 + lrow;
      bf16x8 b0 = bp[0];
      bf16x8 b1 = bp[16];
      bf16x8 b2 = bp[32];
      bf16x8 a[4];
#pragma unroll
      for (int s = 0; s < 4; ++s) {
        int arow = s * 16 + lrow;
        int abyte = ((arow * BK + t * 32 + lhi * 8) * 2) ^ ((arow & 7) << 4);
        a[s] = *(const bf16x8*)(Ab + abyte);
      }
#pragma unroll
      for (int s = 0; s < 4; ++s) {
        acc[s][0] = __builtin_amdgcn_mfma_f32_16x16x32_bf16(a[s], b0, acc[s][0], 0, 0, 0);
        acc[s][1] = __builtin_amdgcn_mfma_f32_16x16x32_bf16(a[s], b1, acc[s][1], 0, 0, 0);
        acc[s][2] = __builtin_amdgcn_mfma_f32_16x16x32_bf16(a[s], b2, acc[s][2], 0, 0, 0);
      }
    }
    if (c + 1 < NC) {
      // buf[(c+1)&1]'s last reader was MFMA(c-1), fenced by the previous barrier:
      // safe to commit without a pre-barrier. One barrier per chunk.
      if (((c + 1) & 1) == 0) { COMMIT_CHUNK(0, pfA, phA) }
      else                    { COMMIT_CHUNK(1, pfB, phB) }
      __syncthreads();
    }
  }
#undef LOAD_CHUNK
#undef COMMIT_CHUNK

  // C/D: col = lane&15, row = (lane>>4)*4 + reg   [m89]
#pragma unroll
  for (int s = 0; s < 4; ++s) {
#pragma unroll
    for (int cc = 0; cc < 3; ++cc) {
#pragma unroll
      for (int j = 0; j < 4; ++j) {
        int r = row0 + s * 16 + lhi * 4 + j;
        if (r < N) Y[(size_t)r * NCOL + wid * 48 + cc * 16 + lrow] = f2bf(acc[s][cc][j]);
      }
    }
  }
}

// ---------------- fused per-node aggregation (8 edges per gather instr) ----------------
template <int RELU, int GATH>
__global__ __launch_bounds__(256) void fused_agg(const ushort* __restrict__ Y,
                                                 const int* __restrict__ rowptr,
                                                 const int* __restrict__ partial,
                                                 const int* __restrict__ srcpk,
                                                 const float* __restrict__ bias,
                                                 const float* __restrict__ gw,
                                                 ushort* __restrict__ accout,
                                                 float* __restrict__ hval, int N) {
  int n = blockIdx.x * 4 + (threadIdx.x >> 6);
  if (n >= N) return;
  const int lane = threadIdx.x & 63;
  const int g    = lane >> 3;        // edge slot 0..7
  const int f0   = (lane & 7) * 8;   // feature slice

  float a0[8], a1[8];
#pragma unroll
  for (int j = 0; j < 8; ++j) { a0[j] = 0.f; a1[j] = 0.f; }
  float c0 = 0.f, c1 = 0.f;

  const int beg = rowptr[n] + partial[n >> 10];
  const int end = rowptr[n + 1] + partial[(n + 1) >> 10];
  for (int i = beg; i < end; i += 16) {
    int eA = i + g, eB = i + 8 + g;
    bool vA = eA < end, vB = eB < end;
    int pkA = 0, pkB = 0;
    if (vA) pkA = srcpk[eA];
    if (vB) pkB = srcpk[eB];
    u16x8 xA = (u16x8){0, 0, 0, 0, 0, 0, 0, 0}, xB = xA;
    if (vA) xA = *(const u16x8*)(Y + (size_t)(pkA & 0x3fffffff) * NCOL + 64 +
                                 ((pkA >> 30) << 6) + f0);
    if (vB) xB = *(const u16x8*)(Y + (size_t)(pkB & 0x3fffffff) * NCOL + 64 +
                                 ((pkB >> 30) << 6) + f0);
    float rA = (vA && (pkA >> 30)) ? 1.f : 0.f;
    float sA = vA ? 1.f : 0.f;
    float rB = (vB && (pkB >> 30)) ? 1.f : 0.f;
    float sB = vB ? 1.f : 0.f;
    c0 += (sA - rA) + (sB - rB);
    c1 += rA + rB;
#pragma unroll
    for (int j = 0; j < 8; ++j) {
      float fA = bf2f(xA[j]), fB = bf2f(xB[j]);
      a0[j] += (sA - rA) * fA + (sB - rB) * fB;
      a1[j] += rA * fA + rB * fB;
    }
  }

  // fold the 8 edge-groups
#pragma unroll
  for (int msk = 8; msk <= 32; msk <<= 1) {
#pragma unroll
    for (int j = 0; j < 8; ++j) {
      a0[j] += __shfl_xor(a0[j], msk);
      a1[j] += __shfl_xor(a1[j], msk);
    }
    c0 += __shfl_xor(c0, msk);
    c1 += __shfl_xor(c1, msk);
  }

  float inv0 = 1.f / fmaxf(c0, 1.f);
  float inv1 = 1.f / fmaxf(c1, 1.f);
  u16x8 rv = *(const u16x8*)(Y + (size_t)n * NCOL + f0);
  float4 bA = *(const float4*)(bias + f0);
  float4 bB = *(const float4*)(bias + f0 + 4);
  float bb[8] = {bA.x, bA.y, bA.z, bA.w, bB.x, bB.y, bB.z, bB.w};
  float res[8];
#pragma unroll
  for (int j = 0; j < 8; ++j) {
    float v = bf2f(rv[j]) + bb[j] + a0[j] * inv0 + a1[j] * inv1;
    res[j] = RELU ? fmaxf(v, 0.f) : v;
  }
  if (accout && g == 0) {
    u16x8 o;
#pragma unroll
    for (int j = 0; j < 8; ++j) o[j] = f2bf(res[j]);
    *(u16x8*)(accout + (size_t)n * 64 + f0) = o;
  }
  if (GATH) {
    float4 gA = *(const float4*)(gw + f0);
    float4 gB = *(const float4*)(gw + f0 + 4);
    float gg[8] = {gA.x, gA.y, gA.z, gA.w, gB.x, gB.y, gB.z, gB.w};
    float dot = 0.f;
#pragma unroll
    for (int j = 0; j < 8; ++j) dot = fmaf(res[j], gg[j], dot);
    dot += __shfl_xor(dot, 1);
    dot += __shfl_xor(dot, 2);
    dot += __shfl_xor(dot, 4);
    if (lane == 0) hval[n] = dot;
  }
}

// ---------------- GAT (CSR, wave per node, lane per edge) ----------------
__device__ __forceinline__ float leaky(float x) { return x > 0.f ? x : 0.2f * x; }

__global__ __launch_bounds__(256) void gat_csr(const int* __restrict__ rowptr,
                                               const int* __restrict__ partial,
                                               const int* __restrict__ srcpk,
                                               const float* __restrict__ hval,
                                               const float* __restrict__ as_,
                                               const float* __restrict__ ad_,
                                               const float* __restrict__ gb,
                                               float* __restrict__ out, int N) {
  int n = blockIdx.x * 4 + (threadIdx.x >> 6);
  if (n >= N) return;
  const int lane = threadIdx.x & 63;
  float as = *as_, ad = *ad_;
  float hv = hval[n];
  float adn = hv * ad;
  float eself = leaky(hv * as + adn);
  const int beg = rowptr[n] + partial[n >> 10];
  const int end = rowptr[n + 1] + partial[(n + 1) >> 10];
  int deg = end - beg;
  float m, den, acc;
  if (deg <= 64) {  // single pass, everything in registers
    bool valid = lane < deg;
    float hs = 0.f;
    if (valid) hs = hval[srcpk[beg + lane] & 0x3fffffff];
    float e = valid ? leaky(hs * as + adn) : -3.4e38f;
    m = fmaxf(e, eself);
#pragma unroll
    for (int o = 32; o > 0; o >>= 1) m = fmaxf(m, __shfl_xor(m, o));
    float ex = valid ? expf(e - m) : 0.f;
    den = ex;
    acc = ex * hs;
#pragma unroll
    for (int o = 32; o > 0; o >>= 1) {
      den += __shfl_xor(den, o);
      acc += __shfl_xor(acc, o);
    }
  } else {  // rare: strided two-pass
    m = eself;
    for (int i = beg + lane; i < end; i += 64)
      m = fmaxf(m, leaky(hval[srcpk[i] & 0x3fffffff] * as + adn));
#pragma unroll
    for (int o = 32; o > 0; o >>= 1) m = fmaxf(m, __shfl_xor(m, o));
    float dl = 0.f, al = 0.f;
    for (int i = beg + lane; i < end; i += 64) {
      float hs = hval[srcpk[i] & 0x3fffffff];
      float ex = expf(leaky(hs * as + adn) - m);
      dl += ex;
      al += ex * hs;
    }
    den = dl;
    acc = al;
#pragma unroll
    for (int o = 32; o > 0; o >>= 1) {
      den += __shfl_xor(den, o);
      acc += __shfl_xor(acc, o);
    }
  }
  float es = expf(eself - m);
  den += es;
  acc += es * hv;
  if (lane == 0) out[n] = acc / den + *gb;
}

// ---------------- launch ----------------
extern "C" void kernel_launch(void* const* d_in, const int* in_sizes, int n_in,
                              void* d_out, int out_size, void* d_ws, size_t ws_size,
                              hipStream_t stream) {
  const float* x      = (const float*)d_in[0];
  const int*   eidx   = (const int*)d_in[1];
  const int*   etype  = (const int*)d_in[2];
  const float* basis1 = (const float*)d_in[3];
  const float* comp1  = (const float*)d_in[4];
  const float* root1  = (const float*)d_in[5];
  const float* bias1  = (const float*)d_in[6];
  const float* basis2 = (const float*)d_in[7];
  const float* comp2  = (const float*)d_in[8];
  const float* root2  = (const float*)d_in[9];
  const float* bias2  = (const float*)d_in[10];
  const float* gat_w  = (const float*)d_in[11];
  const float* att_s  = (const float*)d_in[12];
  const float* att_d  = (const float*)d_in[13];
  const float* gat_b  = (const float*)d_in[14];

  const int N = in_sizes[0] / 512;   // 100000
  const int E = in_sizes[1] / 2;     // 1600000
  const int* src = eidx;
  const int* dst = eidx + E;

  // workspace carve-up (16B-aligned segments)
  char* p = (char*)d_ws;
  ushort* Y    = (ushort*)p; p += (size_t)N * NCOL * 2;        // 38.4 MB (bf16)
  ushort* acc1 = (ushort*)p; p += (size_t)N * 64 * 2;          // 12.8 MB (bf16)
  ushort* Wpk1 = (ushort*)p; p += (size_t)512 * NCOL * 2;      // 196 KB
  ushort* Wpk2 = (ushort*)p; p += (size_t)64 * NCOL * 2;       // 24.6 KB
  float* hval  = (float*)p;  p += (size_t)N * 4;
  int* deg     = (int*)p;    p += (size_t)N * 4;               // zeroed together
  int* fill    = (int*)p;    p += (size_t)N * 4;               //  (one memset)
  int* rowptr  = (int*)p;    p += (size_t)(N + 16) * 4;
  int* partial = (int*)p;    p += (size_t)(SCAN_T + 16) * 4;
  int* srcpk   = (int*)p;    p += (size_t)E * 4;               // 6.4 MB
  float* out   = (float*)d_out;

  const int TB = 256;
  const int GB = (N + 63) / 64;
  const int nb = (N + 1 + SCAN_ELEMS - 1) / SCAN_ELEMS;

  // ---- CSR build (shared by both layers and GAT) ----
  hipMemsetAsync(deg, 0, (size_t)2 * N * sizeof(int), stream);  // deg + fill
  hist_deg<<<(E + TB - 1) / TB, TB, 0, stream>>>(dst, deg, E);
  scan_local<<<nb, SCAN_T, 0, stream>>>(deg, rowptr, partial, N);
  scan_partial<<<1, SCAN_T, 0, stream>>>(partial, nb);
  scatter_edges<<<(E + TB - 1) / TB, TB, 0, stream>>>(src, dst, etype, rowptr, partial,
                                                      fill, srcpk, E);

  // ---- weights (both layers, one dispatch) ----
  build_wpk_both<<<(576 * NCOL + TB - 1) / TB, TB, 0, stream>>>(basis1, comp1, root1,
                                                                basis2, comp2, root2,
                                                                Wpk1, Wpk2);

  // ---- layer 1 (K=512, f32 input) ----
  gemm_mfma<512, 0><<<GB, 256, 0, stream>>>(x, Wpk1, Y, N);
  fused_agg<1, 0><<<(N + 3) / 4, TB, 0, stream>>>(Y, rowptr, partial, srcpk, bias1, nullptr,
                                                  acc1, nullptr, N);

  // ---- layer 2 (K=64, bf16 input) ----
  gemm_mfma<64, 1><<<GB, 256, 0, stream>>>(acc1, Wpk2, Y, N);
  fused_agg<0, 1><<<(N + 3) / 4, TB, 0, stream>>>(Y, rowptr, partial, srcpk, bias2, gat_w,
                                                  nullptr, hval, N);

  // ---- GAT ----
  gat_csr<<<(N + 3) / 4, TB, 0, stream>>>(rowptr, partial, srcpk, hval, att_s, att_d, gat_b,
                                          out, N);
}